// Round 5
// baseline (1976.474 us; speedup 1.0000x reference)
//
#include <hip/hip_runtime.h>
#include <cstdint>
#include <cstddef>

#define S_DIM 12
#define N_NODE 50000
#define N_PAD 50048
#define N_P2 50176
#define D_IN 64
#define D_H 128
#define N_E 600000
#define K_TOT 576   // 128 h + 256 (u1h|u2h) + 64 x + 128 (u1x|u2x)
#define N_COL 512   // 4 gates x 128, interleaved cc = (d&15) + 16*g + 64*(d>>4)
#define HID_P 80
#define N_HID 65
#define AXC 192     // Axt cols: [x | u1x | u2x]

typedef short bf16x8 __attribute__((ext_vector_type(8)));
typedef float f32x4 __attribute__((ext_vector_type(4)));

__device__ __forceinline__ float bf2f(unsigned short u){
  union { unsigned int i; float f; } v; v.i = ((unsigned int)u) << 16; return v.f;
}
__device__ __forceinline__ unsigned short f2bf(float f){
  union { float f; unsigned int i; } v; v.f = f;
  unsigned int x = v.i;
  return (unsigned short)((x + 0x7fffu + ((x >> 16) & 1u)) >> 16);
}
__device__ __forceinline__ float sigf(float x){ return 1.f/(1.f + __expf(-x)); }
__device__ __forceinline__ float ftanh(float x){
  x = fminf(fmaxf(x, -12.f), 12.f);
  float e = __expf(2.f*x);
  return (e - 1.f)/(e + 1.f);
}

__device__ __forceinline__ void gload16(const void* g, void* lds){
  __builtin_amdgcn_global_load_lds((const __attribute__((address_space(1))) unsigned int*)g,
                                   (__attribute__((address_space(3))) unsigned int*)lds, 16, 0, 0);
}

// accumulate 12 bf16 (3 x uint2) * w into a[12]
__device__ __forceinline__ void acc12(float* a, uint2 p0, uint2 p1, uint2 p2, float w){
  unsigned int u[6] = {p0.x, p0.y, p1.x, p1.y, p2.x, p2.y};
#pragma unroll
  for (int i=0;i<6;++i){
    a[2*i]   += w * bf2f((unsigned short)(u[i] & 0xffffu));
    a[2*i+1] += w * bf2f((unsigned short)(u[i] >> 16));
  }
}
// accumulate 8 bf16 (uint4) * w into a[8]
__device__ __forceinline__ void acc8(float* a, uint4 h, float w){
  unsigned int u[4] = {h.x, h.y, h.z, h.w};
#pragma unroll
  for (int i=0;i<4;++i){
    a[2*i]   += w * bf2f((unsigned short)(u[i] & 0xffffu));
    a[2*i+1] += w * bf2f((unsigned short)(u[i] >> 16));
  }
}

// ---------------- prep: pack weights (gate-interleaved cols + Chebyshev fold) ----
__global__ void k_prep(const float* __restrict__ Wx, const float* __restrict__ Wh,
                       const float* __restrict__ bx, const float* __restrict__ bh,
                       const float* __restrict__ bg, const float* __restrict__ W1,
                       const float* __restrict__ b1, const float* __restrict__ W2,
                       unsigned short* __restrict__ Bct, float* __restrict__ btot,
                       unsigned short* __restrict__ W1t, float* __restrict__ b1p,
                       float* __restrict__ W2p)
{
  int idx = blockIdx.x*256 + threadIdx.x;
  if (idx < N_COL*K_TOT){
    int cc = idx / K_TOT, k = idx - cc*K_TOT;
    int g = (cc>>4)&3, d = (cc&15) + ((cc>>6)<<4);
    float v;
    if (k < 384){
      int kt = k >> 7, j = k & 127;
      const float* Wg = Wh + (size_t)g*3*128*128;
      if (kt == 0)      v = Wg[(size_t)j*128 + d] - Wg[(size_t)(256+j)*128 + d];
      else if (kt == 1) v = Wg[(size_t)(128+j)*128 + d];
      else              v = 2.f*Wg[(size_t)(256+j)*128 + d];
    } else {
      int kk = k - 384; int kt = kk >> 6, j = kk & 63;
      const float* Wg = Wx + (size_t)g*3*64*128;
      if (kt == 0)      v = Wg[(size_t)j*128 + d] - Wg[(size_t)(128+j)*128 + d];
      else if (kt == 1) v = Wg[(size_t)(64+j)*128 + d];
      else              v = 2.f*Wg[(size_t)(128+j)*128 + d];
    }
    Bct[(size_t)cc*K_TOT + k] = f2bf(v);
  }
  if (idx < N_COL) btot[idx] = bx[idx] + bh[idx] + bg[idx];
  if (idx < HID_P*D_H){ int c = idx >> 7, k = idx & 127;
    W1t[idx] = (c < N_HID) ? f2bf(W1[k*N_HID + c]) : (unsigned short)0; }
  if (idx < HID_P) b1p[idx] = (idx < N_HID) ? b1[idx] : 0.f;
  if (idx < HID_P*2){ int c = idx >> 1, j = idx & 1; W2p[idx] = (c < N_HID) ? W2[c*2 + j] : 0.f; }
}

// ---------------- x conversion: H -> Xtr [n][d][12] + Axt x-planes ----------------
__global__ void k_xprep(const float* __restrict__ H, unsigned short* __restrict__ Xtr,
                        unsigned short* __restrict__ Axt){
  int idx = blockIdx.x*256 + threadIdx.x;    // (n,d)
  if (idx >= N_PAD*64) return;
  int n = idx >> 6, d = idx & 63;
  union { unsigned short u[12]; uint2 q[3]; } pk;
  if (n < N_NODE){
#pragma unroll
    for (int t=0;t<12;++t) pk.u[t] = f2bf(H[((size_t)t*N_NODE + n)*64 + d]);
  } else {
#pragma unroll
    for (int t=0;t<12;++t) pk.u[t] = 0;
  }
  uint2* xp = (uint2*)(Xtr + (size_t)idx*12);
  xp[0]=pk.q[0]; xp[1]=pk.q[1]; xp[2]=pk.q[2];
#pragma unroll
  for (int t=0;t<12;++t) Axt[((size_t)t*N_PAD + n)*AXC + d] = pk.u[t];
  if (n >= N_NODE){
#pragma unroll
    for (int t=0;t<12;++t){
      Axt[((size_t)t*N_PAD + n)*AXC + 64 + d]  = 0;
      Axt[((size_t)t*N_PAD + n)*AXC + 128 + d] = 0;
    }
  }
}

// ---------------- graph preprocessing ----------------
__global__ void k_deg(const int* __restrict__ ei, int* __restrict__ dsrc, int* __restrict__ ddst){
  int e = blockIdx.x*256 + threadIdx.x;
  if (e < N_E){
    atomicAdd(&dsrc[ei[e]], 1);
    atomicAdd(&ddst[ei[N_E + e]], 1);
  }
}
__global__ void k_dinv(const int* __restrict__ dsrc, float* __restrict__ dinv){
  int n = blockIdx.x*256 + threadIdx.x;
  if (n < N_P2) dinv[n] = (dsrc[n] > 0) ? rsqrtf((float)dsrc[n]) : 0.f;
}
__global__ void k_scan1(const int* __restrict__ in, int* __restrict__ outp, int* __restrict__ part){
  __shared__ int sm[256];
  int tid = threadIdx.x;
  int i = blockIdx.x*256 + tid;
  int v = in[i];
  int x = v;
  sm[tid] = x; __syncthreads();
  for (int off=1; off<256; off<<=1){
    int y = (tid >= off) ? sm[tid-off] : 0;
    __syncthreads();
    x += y; sm[tid] = x; __syncthreads();
  }
  outp[i] = x - v;
  if (tid == 255) part[blockIdx.x] = x;
}
__global__ void k_scan2(int* __restrict__ part, int nblk){
  __shared__ int sm[256];
  int tid = threadIdx.x;
  int v = (tid < nblk) ? part[tid] : 0;
  int x = v; sm[tid] = x; __syncthreads();
  for (int off=1; off<256; off<<=1){
    int y = (tid >= off) ? sm[tid-off] : 0;
    __syncthreads();
    x += y; sm[tid] = x; __syncthreads();
  }
  if (tid < nblk) part[tid] = x - v;
}
__global__ void k_scan3(const int* __restrict__ outp, const int* __restrict__ part, int* __restrict__ offs){
  int i = blockIdx.x*256 + threadIdx.x;
  offs[i] = outp[i] + part[blockIdx.x];
}
__global__ void k_csr(const int* __restrict__ ei, const float* __restrict__ dinv,
                      const int* __restrict__ offs, int* __restrict__ cursor,
                      int2* __restrict__ cedge){
  int e = blockIdx.x*256 + threadIdx.x;
  if (e < N_E){
    int s = ei[e], d = ei[N_E + e];
    int pos = atomicAdd(&cursor[d], 1);
    float w = -dinv[s]*dinv[d];
    cedge[offs[d] + pos] = make_int2(s, __float_as_int(w));
  }
}

// ---------------- x-side spmm, all 12 t at once, 6 edges in flight ----------
__global__ void k_xspmm1(const unsigned short* __restrict__ Xtr, unsigned short* __restrict__ Axt,
                         unsigned short* __restrict__ U1tr,
                         const int* __restrict__ offs, const int2* __restrict__ cedge){
  int n = blockIdx.x*4 + (threadIdx.x >> 6);
  int l = threadIdx.x & 63;
  if (n >= N_NODE) return;
  int beg = offs[n], end = offs[n+1];
  int ce = end - 1;
  float a[12];
#pragma unroll
  for (int t=0;t<12;++t) a[t] = 0.f;
  for (int q = beg; q < end; q += 6){
    int2 e0 = cedge[min(q,   ce)];
    int2 e1 = cedge[min(q+1, ce)];
    int2 e2 = cedge[min(q+2, ce)];
    int2 e3 = cedge[min(q+3, ce)];
    int2 e4 = cedge[min(q+4, ce)];
    int2 e5 = cedge[min(q+5, ce)];
    float w0 = __int_as_float(e0.y);
    float w1 = (q+1 < end) ? __int_as_float(e1.y) : 0.f;
    float w2 = (q+2 < end) ? __int_as_float(e2.y) : 0.f;
    float w3 = (q+3 < end) ? __int_as_float(e3.y) : 0.f;
    float w4 = (q+4 < end) ? __int_as_float(e4.y) : 0.f;
    float w5 = (q+5 < end) ? __int_as_float(e5.y) : 0.f;
    const uint2* r0 = (const uint2*)(Xtr + ((size_t)e0.x*64 + l)*12);
    const uint2* r1 = (const uint2*)(Xtr + ((size_t)e1.x*64 + l)*12);
    const uint2* r2 = (const uint2*)(Xtr + ((size_t)e2.x*64 + l)*12);
    const uint2* r3 = (const uint2*)(Xtr + ((size_t)e3.x*64 + l)*12);
    const uint2* r4 = (const uint2*)(Xtr + ((size_t)e4.x*64 + l)*12);
    const uint2* r5 = (const uint2*)(Xtr + ((size_t)e5.x*64 + l)*12);
    uint2 p00=r0[0], p01=r0[1], p02=r0[2];
    uint2 p10=r1[0], p11=r1[1], p12=r1[2];
    uint2 p20=r2[0], p21=r2[1], p22=r2[2];
    uint2 p30=r3[0], p31=r3[1], p32=r3[2];
    uint2 p40=r4[0], p41=r4[1], p42=r4[2];
    uint2 p50=r5[0], p51=r5[1], p52=r5[2];
    acc12(a, p00, p01, p02, w0);
    acc12(a, p10, p11, p12, w1);
    acc12(a, p20, p21, p22, w2);
    acc12(a, p30, p31, p32, w3);
    acc12(a, p40, p41, p42, w4);
    acc12(a, p50, p51, p52, w5);
  }
  union { unsigned short u[12]; uint2 qq[3]; } pk;
#pragma unroll
  for (int t=0;t<12;++t){
    unsigned short b = f2bf(a[t]);
    pk.u[t] = b;
    Axt[((size_t)t*N_PAD + n)*AXC + 64 + l] = b;
  }
  uint2* op = (uint2*)(U1tr + ((size_t)n*64 + l)*12);
  op[0]=pk.qq[0]; op[1]=pk.qq[1]; op[2]=pk.qq[2];
}
__global__ void k_xspmm2(const unsigned short* __restrict__ U1tr, unsigned short* __restrict__ Axt,
                         const int* __restrict__ offs, const int2* __restrict__ cedge){
  int n = blockIdx.x*4 + (threadIdx.x >> 6);
  int l = threadIdx.x & 63;
  if (n >= N_NODE) return;
  int beg = offs[n], end = offs[n+1];
  int ce = end - 1;
  float a[12];
#pragma unroll
  for (int t=0;t<12;++t) a[t] = 0.f;
  for (int q = beg; q < end; q += 6){
    int2 e0 = cedge[min(q,   ce)];
    int2 e1 = cedge[min(q+1, ce)];
    int2 e2 = cedge[min(q+2, ce)];
    int2 e3 = cedge[min(q+3, ce)];
    int2 e4 = cedge[min(q+4, ce)];
    int2 e5 = cedge[min(q+5, ce)];
    float w0 = __int_as_float(e0.y);
    float w1 = (q+1 < end) ? __int_as_float(e1.y) : 0.f;
    float w2 = (q+2 < end) ? __int_as_float(e2.y) : 0.f;
    float w3 = (q+3 < end) ? __int_as_float(e3.y) : 0.f;
    float w4 = (q+4 < end) ? __int_as_float(e4.y) : 0.f;
    float w5 = (q+5 < end) ? __int_as_float(e5.y) : 0.f;
    const uint2* r0 = (const uint2*)(U1tr + ((size_t)e0.x*64 + l)*12);
    const uint2* r1 = (const uint2*)(U1tr + ((size_t)e1.x*64 + l)*12);
    const uint2* r2 = (const uint2*)(U1tr + ((size_t)e2.x*64 + l)*12);
    const uint2* r3 = (const uint2*)(U1tr + ((size_t)e3.x*64 + l)*12);
    const uint2* r4 = (const uint2*)(U1tr + ((size_t)e4.x*64 + l)*12);
    const uint2* r5 = (const uint2*)(U1tr + ((size_t)e5.x*64 + l)*12);
    uint2 p00=r0[0], p01=r0[1], p02=r0[2];
    uint2 p10=r1[0], p11=r1[1], p12=r1[2];
    uint2 p20=r2[0], p21=r2[1], p22=r2[2];
    uint2 p30=r3[0], p31=r3[1], p32=r3[2];
    uint2 p40=r4[0], p41=r4[1], p42=r4[2];
    uint2 p50=r5[0], p51=r5[1], p52=r5[2];
    acc12(a, p00, p01, p02, w0);
    acc12(a, p10, p11, p12, w1);
    acc12(a, p20, p21, p22, w2);
    acc12(a, p30, p31, p32, w3);
    acc12(a, p40, p41, p42, w4);
    acc12(a, p50, p51, p52, w5);
  }
#pragma unroll
  for (int t=0;t<12;++t)
    Axt[((size_t)t*N_PAD + n)*AXC + 128 + l] = f2bf(a[t]);
}

// ---------------- per-step h-side spmm: 16 edges in flight, clamp tail ----------
__global__ void k_spmm1(const unsigned short* __restrict__ Hc, unsigned short* __restrict__ U,
                        const int* __restrict__ offs, const int2* __restrict__ cedge){
  int n = blockIdx.x*4 + (threadIdx.x >> 6);
  int l = threadIdx.x & 63;
  if (n >= N_NODE) return;
  int sub = l >> 4, fl = l & 15;
  int beg = offs[n], end = offs[n+1];
  int ce = end - 1;
  float a[8];
#pragma unroll
  for (int j=0;j<8;++j) a[j] = 0.f;
  for (int q = beg; q < end; q += 16){
    int i0 = q + sub, i1 = q + 4 + sub, i2 = q + 8 + sub, i3 = q + 12 + sub;
    int2 e0 = cedge[min(i0, ce)];
    int2 e1 = cedge[min(i1, ce)];
    int2 e2 = cedge[min(i2, ce)];
    int2 e3 = cedge[min(i3, ce)];
    float w0 = (i0 < end) ? __int_as_float(e0.y) : 0.f;
    float w1 = (i1 < end) ? __int_as_float(e1.y) : 0.f;
    float w2 = (i2 < end) ? __int_as_float(e2.y) : 0.f;
    float w3 = (i3 < end) ? __int_as_float(e3.y) : 0.f;
    uint4 h0 = *(const uint4*)(Hc + (size_t)e0.x*128 + fl*8);
    uint4 h1 = *(const uint4*)(Hc + (size_t)e1.x*128 + fl*8);
    uint4 h2 = *(const uint4*)(Hc + (size_t)e2.x*128 + fl*8);
    uint4 h3 = *(const uint4*)(Hc + (size_t)e3.x*128 + fl*8);
    acc8(a, h0, w0);
    acc8(a, h1, w1);
    acc8(a, h2, w2);
    acc8(a, h3, w3);
  }
#pragma unroll
  for (int j=0;j<8;++j){
    a[j] += __shfl_xor(a[j], 16);
    a[j] += __shfl_xor(a[j], 32);
  }
  if (sub == 0){
    unsigned short o[8];
#pragma unroll
    for (int j=0;j<8;++j) o[j] = f2bf(a[j]);
    *(uint4*)(U + (size_t)n*256 + fl*8) = *(const uint4*)o;
  }
}
__global__ void k_spmm2(unsigned short* __restrict__ U,
                        const int* __restrict__ offs, const int2* __restrict__ cedge){
  int n = blockIdx.x*4 + (threadIdx.x >> 6);
  int l = threadIdx.x & 63;
  if (n >= N_NODE) return;
  int sub = l >> 4, fl = l & 15;
  int beg = offs[n], end = offs[n+1];
  int ce = end - 1;
  float a[8];
#pragma unroll
  for (int j=0;j<8;++j) a[j] = 0.f;
  for (int q = beg; q < end; q += 16){
    int i0 = q + sub, i1 = q + 4 + sub, i2 = q + 8 + sub, i3 = q + 12 + sub;
    int2 e0 = cedge[min(i0, ce)];
    int2 e1 = cedge[min(i1, ce)];
    int2 e2 = cedge[min(i2, ce)];
    int2 e3 = cedge[min(i3, ce)];
    float w0 = (i0 < end) ? __int_as_float(e0.y) : 0.f;
    float w1 = (i1 < end) ? __int_as_float(e1.y) : 0.f;
    float w2 = (i2 < end) ? __int_as_float(e2.y) : 0.f;
    float w3 = (i3 < end) ? __int_as_float(e3.y) : 0.f;
    uint4 h0 = *(const uint4*)(U + (size_t)e0.x*256 + fl*8);
    uint4 h1 = *(const uint4*)(U + (size_t)e1.x*256 + fl*8);
    uint4 h2 = *(const uint4*)(U + (size_t)e2.x*256 + fl*8);
    uint4 h3 = *(const uint4*)(U + (size_t)e3.x*256 + fl*8);
    acc8(a, h0, w0);
    acc8(a, h1, w1);
    acc8(a, h2, w2);
    acc8(a, h3, w3);
  }
#pragma unroll
  for (int j=0;j<8;++j){
    a[j] += __shfl_xor(a[j], 16);
    a[j] += __shfl_xor(a[j], 32);
  }
  if (sub == 0){
    unsigned short o[8];
#pragma unroll
    for (int j=0;j<8;++j) o[j] = f2bf(a[j]);
    *(uint4*)(U + (size_t)n*256 + 128 + fl*8) = *(const uint4*)o;
  }
}

// ---------------- fused GEMM + LSTM gates (double-buffered, 1 barrier/K-step) ----
__global__ __launch_bounds__(256,2) void k_gemm(
    const unsigned short* __restrict__ Hc, const unsigned short* __restrict__ U,
    const unsigned short* __restrict__ Axt,
    const unsigned short* __restrict__ Bct, const float* __restrict__ btot,
    const float* __restrict__ wc, float* __restrict__ c, unsigned short* __restrict__ Hn)
{
  __shared__ __align__(16) unsigned short As[2][128*64];
  __shared__ __align__(16) unsigned short Bs[2][128*64];
  int tid = threadIdx.x;
  int w = tid >> 6, l = tid & 63;
  const int NWG = 1564, q8 = NWG >> 3, r8 = NWG & 7;
  int L = blockIdx.y*4 + blockIdx.x;
  int xcd = L & 7, li = L >> 3;
  int W = (xcd < r8 ? xcd*(q8+1) : r8*(q8+1) + (xcd-r8)*q8) + li;
  int bx = W & 3, by = W >> 2;
  int n0 = bx * 128;
  int m0 = by * 128;
  const f32x4 vzero = {0.f,0.f,0.f,0.f};
  f32x4 acc[4][4];
#pragma unroll
  for (int i=0;i<4;++i)
#pragma unroll
    for (int j=0;j<4;++j) acc[i][j] = vzero;
  int wr = w >> 1, wn = w & 1;

  auto stage = [&](int buf, int it){
    const unsigned short* Ab; int astr, acol;
    if (it < 2)      { Ab = Hc;  astr = 128; acol = it*64; }
    else if (it < 6) { Ab = U;   astr = 256; acol = (it-2)*64; }
    else             { Ab = Axt; astr = AXC; acol = (it-6)*64; }
#pragma unroll
    for (int i=0;i<4;++i){
      int rr = w*32 + i*8;
      int row = rr + (l>>3);
      gload16(Ab  + (size_t)(m0+row)*astr + acol + (l&7)*8, (void*)(As[buf] + rr*64));
      gload16(Bct + (size_t)(n0+row)*K_TOT + it*64 + (l&7)*8, (void*)(Bs[buf] + rr*64));
    }
  };

  stage(0, 0);
  __syncthreads();   // compiler emits vmcnt(0) drain before s_barrier
  for (int it=0; it<9; ++it){
    int cur = it & 1;
    if (it < 8) stage(cur^1, it+1);
#pragma unroll
    for (int kk=0; kk<2; ++kk){
      bf16x8 af[4], bfv[4];
#pragma unroll
      for (int i=0;i<4;++i) af[i]  = *(const bf16x8*)(As[cur] + (wr*64 + i*16 + (l&15))*64 + kk*32 + (l>>4)*8);
#pragma unroll
      for (int j=0;j<4;++j) bfv[j] = *(const bf16x8*)(Bs[cur] + (wn*64 + j*16 + (l&15))*64 + kk*32 + (l>>4)*8);
#pragma unroll
      for (int i=0;i<4;++i)
#pragma unroll
        for (int j=0;j<4;++j)
          acc[i][j] = __builtin_amdgcn_mfma_f32_16x16x32_bf16(af[i], bfv[j], acc[i][j], 0,0,0);
    }
    __syncthreads();   // drains vmcnt (next buf staged) + protects cur buf reuse
  }
  int dd = (((bx<<1) + wn) << 4) | (l & 15);
  float b_i = btot[dd], b_f = btot[128+dd], b_t = btot[256+dd], b_o = btot[384+dd];
  float wci = wc[dd], wcf = wc[128+dd], wco = wc[256+dd];
#pragma unroll
  for (int i=0;i<4;++i){
    int row0 = m0 + wr*64 + i*16 + (l>>4)*4;
#pragma unroll
    for (int r=0;r<4;++r){
      int row = row0 + r;
      float co = c[(size_t)row*128 + dd];
      float gi = sigf(acc[i][0][r] + b_i + wci*co);
      float gf = sigf(acc[i][1][r] + b_f + wcf*co);
      float tt = ftanh(acc[i][2][r] + b_t);
      float cn = gf*co + gi*tt;
      float go = sigf(acc[i][3][r] + b_o + wco*cn);
      float h = go * ftanh(cn);
      c[(size_t)row*128 + dd] = cn;
      Hn[(size_t)row*128 + dd] = f2bf(h);
    }
  }
}

// ---------------- tanh + LN + MLP + sigmoid + transpose (per step) ----------------
__global__ __launch_bounds__(256,2) void k_lnmlp(const unsigned short* __restrict__ Hn,
                        const unsigned short* __restrict__ W1t, const float* __restrict__ b1p,
                        const float* __restrict__ W2p, const float* __restrict__ b2,
                        const float* __restrict__ gam, const float* __restrict__ bet,
                        float* __restrict__ out, int t)
{
  __shared__ __align__(16) unsigned short xn[64*128];
  __shared__ __align__(16) unsigned short w1s[HID_P*128];
  __shared__ float w2s[HID_P*2];
  __shared__ float b1s[HID_P];
  __shared__ float b2s[2];
  int tid = threadIdx.x;
  for (int i = tid; i < HID_P*128/8; i += 256) ((int4*)w1s)[i] = ((const int4*)W1t)[i];
  if (tid < HID_P*2) w2s[tid] = W2p[tid];
  if (tid < HID_P)   b1s[tid] = b1p[tid];
  if (tid < 2)       b2s[tid] = b2[tid];
  int n0 = blockIdx.x*64;
  int row = tid >> 2, part = tid & 3;
  int n = n0 + row;
  float vals[32];
  float s = 0.f, ss = 0.f;
  if (n < N_NODE){
    const unsigned short* hp = Hn + (size_t)n*128 + part*32;
#pragma unroll
    for (int k=0;k<32;++k){
      float x = ftanh(bf2f(hp[k]));
      vals[k] = x; s += x; ss += x*x;
    }
  } else {
#pragma unroll
    for (int k=0;k<32;++k) vals[k] = 0.f;
  }
  s  += __shfl_xor(s,1);  s  += __shfl_xor(s,2);
  ss += __shfl_xor(ss,1); ss += __shfl_xor(ss,2);
  float mu = s * (1.f/128.f);
  float var = ss * (1.f/128.f) - mu*mu;
  float inv = rsqrtf(fmaxf(var, 0.f) + 1e-5f);
#pragma unroll
  for (int k=0;k<32;++k){
    int d = part*32 + k;
    xn[row*128 + d] = f2bf((vals[k]-mu)*inv*gam[d] + bet[d]);
  }
  __syncthreads();
  int w = tid >> 6, l = tid & 63;
  const f32x4 vzero = {0.f,0.f,0.f,0.f};
  f32x4 acc[5];
#pragma unroll
  for (int tj=0;tj<5;++tj) acc[tj] = vzero;
#pragma unroll
  for (int kk=0;kk<4;++kk){
    bf16x8 a = *(const bf16x8*)(xn + (w*16 + (l&15))*128 + kk*32 + (l>>4)*8);
#pragma unroll
    for (int tj=0;tj<5;++tj){
      bf16x8 b = *(const bf16x8*)(w1s + (tj*16 + (l&15))*128 + kk*32 + (l>>4)*8);
      acc[tj] = __builtin_amdgcn_mfma_f32_16x16x32_bf16(a, b, acc[tj], 0,0,0);
    }
  }
#pragma unroll
  for (int r=0;r<4;++r){
    int rn = n0 + w*16 + (l>>4)*4 + r;
    float p0 = 0.f, p1 = 0.f;
#pragma unroll
    for (int tj=0;tj<5;++tj){
      int col = tj*16 + (l&15);
      float hv = fmaxf(acc[tj][r] + b1s[col], 0.f);
      p0 += hv * w2s[col*2];
      p1 += hv * w2s[col*2+1];
    }
    p0 += __shfl_xor(p0,1); p0 += __shfl_xor(p0,2); p0 += __shfl_xor(p0,4); p0 += __shfl_xor(p0,8);
    p1 += __shfl_xor(p1,1); p1 += __shfl_xor(p1,2); p1 += __shfl_xor(p1,4); p1 += __shfl_xor(p1,8);
    if ((l & 15) == 0 && rn < N_NODE){
      float* op = out + (size_t)rn*24 + t;   // out[n][c][s], C=2, S=12
      op[0]  = sigf(p0 + b2s[0]);
      op[12] = sigf(p1 + b2s[1]);
    }
  }
}

extern "C" void kernel_launch(void* const* d_in, const int* in_sizes, int n_in,
                              void* d_out, int out_size, void* d_ws, size_t ws_size,
                              hipStream_t stream)
{
  const float* H   = (const float*)d_in[0];
  const int*   ei  = (const int*)d_in[1];
  const float* Wx  = (const float*)d_in[2];
  const float* bx  = (const float*)d_in[3];
  const float* Wh  = (const float*)d_in[4];
  const float* bh  = (const float*)d_in[5];
  const float* bg  = (const float*)d_in[6];
  const float* wc  = (const float*)d_in[7];
  const float* gam = (const float*)d_in[8];
  const float* bet = (const float*)d_in[9];
  const float* W1  = (const float*)d_in[10];
  const float* b1  = (const float*)d_in[11];
  const float* W2  = (const float*)d_in[12];
  const float* b2  = (const float*)d_in[13];
  float* out = (float*)d_out;
  (void)in_sizes; (void)n_in; (void)out_size; (void)ws_size;

  char* p = (char*)d_ws;
  auto alloc = [&](size_t bytes)->char*{ char* r = p; p += (bytes + 255) & ~(size_t)255; return r; };
  // ---- zeroed region (one memset) ----
  char* zbase = p;
  float*          c_st  = (float*)alloc((size_t)N_PAD*128*4);
  unsigned short* Hbuf0 = (unsigned short*)alloc((size_t)N_PAD*128*2);
  unsigned short* Ubuf  = (unsigned short*)alloc((size_t)N_PAD*256*2);
  int* dsrc   = (int*)alloc((size_t)N_P2*4);
  int* ddst   = (int*)alloc((size_t)N_P2*4);
  int* cursor = (int*)alloc((size_t)N_P2*4);
  size_t zbytes = (size_t)(p - zbase);
  // ---- rest ----
  unsigned short* Hbuf1 = (unsigned short*)alloc((size_t)N_PAD*128*2);
  unsigned short* Xtr   = (unsigned short*)alloc((size_t)N_PAD*64*12*2);
  unsigned short* U1tr  = (unsigned short*)alloc((size_t)N_PAD*64*12*2);
  unsigned short* Axt   = (unsigned short*)alloc((size_t)S_DIM*N_PAD*AXC*2);
  unsigned short* Bct   = (unsigned short*)alloc((size_t)N_COL*K_TOT*2);
  float*          btot  = (float*)alloc(N_COL*4);
  unsigned short* W1t   = (unsigned short*)alloc(HID_P*128*2);
  float*          b1p   = (float*)alloc(HID_P*4);
  float*          W2p   = (float*)alloc(HID_P*2*4);
  float*          dinv  = (float*)alloc((size_t)N_P2*4);
  int*            offs  = (int*)alloc((size_t)(N_P2+256)*4);
  int*            outp  = (int*)alloc((size_t)N_P2*4);
  int*            partb = (int*)alloc(256*4);
  int2*           cedge = (int2*)alloc((size_t)N_E*8);

  hipMemsetAsync(zbase, 0, zbytes, stream);
  k_prep<<<(N_COL*K_TOT + 255)/256, 256, 0, stream>>>(Wx, Wh, bx, bh, bg, W1, b1, W2,
                                                      Bct, btot, W1t, b1p, W2p);
  k_xprep<<<(N_PAD*64 + 255)/256, 256, 0, stream>>>(H, Xtr, Axt);
  k_deg<<<(N_E + 255)/256, 256, 0, stream>>>(ei, dsrc, ddst);
  k_dinv<<<N_P2/256, 256, 0, stream>>>(dsrc, dinv);
  k_scan1<<<N_P2/256, 256, 0, stream>>>(ddst, outp, partb);
  k_scan2<<<1, 256, 0, stream>>>(partb, N_P2/256);
  k_scan3<<<N_P2/256, 256, 0, stream>>>(outp, partb, offs);
  k_csr<<<(N_E + 255)/256, 256, 0, stream>>>(ei, dinv, offs, cursor, cedge);
  k_xspmm1<<<N_NODE/4, 256, 0, stream>>>(Xtr, Axt, U1tr, offs, cedge);
  k_xspmm2<<<N_NODE/4, 256, 0, stream>>>(U1tr, Axt, offs, cedge);

  for (int t = 0; t < S_DIM; ++t){
    unsigned short* Hc = (t & 1) ? Hbuf1 : Hbuf0;
    unsigned short* Hn = (t & 1) ? Hbuf0 : Hbuf1;
    if (t > 0){   // h==0 at t=0 -> u1h=u2h=0 (Ubuf pre-zeroed)
      k_spmm1<<<N_NODE/4, 256, 0, stream>>>(Hc, Ubuf, offs, cedge);
      k_spmm2<<<N_NODE/4, 256, 0, stream>>>(Ubuf, offs, cedge);
    }
    k_gemm<<<dim3(4, N_PAD/128), 256, 0, stream>>>(Hc, Ubuf,
        Axt + (size_t)t*N_PAD*AXC, Bct, btot, wc, c_st, Hn);
    k_lnmlp<<<N_PAD/64, 256, 0, stream>>>(Hn, W1t, b1p, W2p, b2, gam, bet, out, t);
  }
}

// Round 6
// 1860.142 us; speedup vs baseline: 1.0625x; 1.0625x over previous
//
#include <hip/hip_runtime.h>
#include <cstdint>
#include <cstddef>

#define S_DIM 12
#define N_NODE 50000
#define N_PAD 50048
#define N_P2 50176
#define D_IN 64
#define D_H 128
#define N_E 600000
#define K_TOT 576
#define N_COL 512
#define HID_P 80
#define N_HID 65
#define AXC 192

#define NB_PREP 1152
#define NB_XPREP 12512
#define NB_DEG 2344
#define NB_SPMM 12500
#define NB_LN 782

typedef short bf16x8 __attribute__((ext_vector_type(8)));
typedef float f32x4 __attribute__((ext_vector_type(4)));

__device__ __forceinline__ float bf2f(unsigned short u){
  union { unsigned int i; float f; } v; v.i = ((unsigned int)u) << 16; return v.f;
}
__device__ __forceinline__ unsigned short f2bf(float f){
  union { float f; unsigned int i; } v; v.f = f;
  unsigned int x = v.i;
  return (unsigned short)((x + 0x7fffu + ((x >> 16) & 1u)) >> 16);
}
__device__ __forceinline__ float sigf(float x){ return 1.f/(1.f + __expf(-x)); }
__device__ __forceinline__ float ftanh(float x){
  x = fminf(fmaxf(x, -12.f), 12.f);
  float e = __expf(2.f*x);
  return (e - 1.f)/(e + 1.f);
}
__device__ __forceinline__ void gload16(const void* g, void* lds){
  __builtin_amdgcn_global_load_lds((const __attribute__((address_space(1))) unsigned int*)g,
                                   (__attribute__((address_space(3))) unsigned int*)lds, 16, 0, 0);
}
// accumulate 6 bf16 (3 dwords) * w
__device__ __forceinline__ void acc6(float* a, unsigned int p0, unsigned int p1, unsigned int p2, float w){
  unsigned int u[3] = {p0, p1, p2};
#pragma unroll
  for (int i=0;i<3;++i){
    a[2*i]   += w * bf2f((unsigned short)(u[i] & 0xffffu));
    a[2*i+1] += w * bf2f((unsigned short)(u[i] >> 16));
  }
}
// accumulate 8 bf16 (uint4) * w
__device__ __forceinline__ void acc8(float* a, uint4 h, float w){
  unsigned int u[4] = {h.x, h.y, h.z, h.w};
#pragma unroll
  for (int i=0;i<4;++i){
    a[2*i]   += w * bf2f((unsigned short)(u[i] & 0xffffu));
    a[2*i+1] += w * bf2f((unsigned short)(u[i] >> 16));
  }
}

// ---------------- fused setup: weight pack + x convert + degree count ----------
__global__ void k_setup(const float* __restrict__ H, const int* __restrict__ ei,
                        const float* __restrict__ Wx, const float* __restrict__ Wh,
                        const float* __restrict__ bx, const float* __restrict__ bh,
                        const float* __restrict__ bg, const float* __restrict__ W1,
                        const float* __restrict__ b1, const float* __restrict__ W2,
                        unsigned short* __restrict__ Bct, float* __restrict__ btot,
                        unsigned short* __restrict__ W1t, float* __restrict__ b1p,
                        float* __restrict__ W2p, unsigned short* __restrict__ Xtr,
                        unsigned short* __restrict__ Axt,
                        int* __restrict__ dsrc, int* __restrict__ ddst)
{
  int bb = blockIdx.x, tid = threadIdx.x;
  if (bb < NB_PREP){
    int idx = bb*256 + tid;
    if (idx < N_COL*K_TOT){
      int cc = idx / K_TOT, k = idx - cc*K_TOT;
      int g = (cc>>4)&3, d = (cc&15) + ((cc>>6)<<4);
      float v;
      if (k < 384){
        int kt = k >> 7, j = k & 127;
        const float* Wg = Wh + (size_t)g*3*128*128;
        if (kt == 0)      v = Wg[(size_t)j*128 + d] - Wg[(size_t)(256+j)*128 + d];
        else if (kt == 1) v = Wg[(size_t)(128+j)*128 + d];
        else              v = 2.f*Wg[(size_t)(256+j)*128 + d];
      } else {
        int kk = k - 384; int kt = kk >> 6, j = kk & 63;
        const float* Wg = Wx + (size_t)g*3*64*128;
        if (kt == 0)      v = Wg[(size_t)j*128 + d] - Wg[(size_t)(128+j)*128 + d];
        else if (kt == 1) v = Wg[(size_t)(64+j)*128 + d];
        else              v = 2.f*Wg[(size_t)(128+j)*128 + d];
      }
      Bct[(size_t)cc*K_TOT + k] = f2bf(v);
    }
    if (idx < N_COL) btot[idx] = bx[idx] + bh[idx] + bg[idx];
    if (idx < HID_P*D_H){ int c = idx >> 7, k = idx & 127;
      W1t[idx] = (c < N_HID) ? f2bf(W1[k*N_HID + c]) : (unsigned short)0; }
    if (idx < HID_P) b1p[idx] = (idx < N_HID) ? b1[idx] : 0.f;
    if (idx < HID_P*2){ int c = idx >> 1, j = idx & 1; W2p[idx] = (c < N_HID) ? W2[c*2 + j] : 0.f; }
  } else if (bb < NB_PREP + NB_XPREP){
    int idx = (bb - NB_PREP)*256 + tid;      // (n,d)
    int n = idx >> 6, d = idx & 63;
    unsigned short u[12];
    if (n < N_NODE){
#pragma unroll
      for (int t=0;t<12;++t) u[t] = f2bf(H[((size_t)t*N_NODE + n)*64 + d]);
    } else {
#pragma unroll
      for (int t=0;t<12;++t) u[t] = 0;
    }
    // Xtr halves: [h][n*64+d][6] dense
    unsigned int* x0 = (unsigned int*)(Xtr + (size_t)idx*6);
    unsigned int* x1 = (unsigned int*)(Xtr + (size_t)N_PAD*384 + (size_t)idx*6);
#pragma unroll
    for (int i=0;i<3;++i){
      x0[i] = (unsigned int)u[2*i]   | ((unsigned int)u[2*i+1] << 16);
      x1[i] = (unsigned int)u[6+2*i] | ((unsigned int)u[6+2*i+1] << 16);
    }
#pragma unroll
    for (int t=0;t<12;++t) Axt[((size_t)t*N_PAD + n)*AXC + d] = u[t];
    if (n >= N_NODE){
#pragma unroll
      for (int t=0;t<12;++t){
        Axt[((size_t)t*N_PAD + n)*AXC + 64 + d]  = 0;
        Axt[((size_t)t*N_PAD + n)*AXC + 128 + d] = 0;
      }
    }
  } else {
    int e = (bb - NB_PREP - NB_XPREP)*256 + tid;
    if (e < N_E){
      atomicAdd(&dsrc[ei[e]], 1);
      atomicAdd(&ddst[ei[N_E + e]], 1);
    }
  }
}

// ---------------- scans + csr ----------------
__global__ void k_scan1d(const int* __restrict__ in, int* __restrict__ outp, int* __restrict__ part,
                         const int* __restrict__ dsrc, float* __restrict__ dinv){
  __shared__ int sm[256];
  int tid = threadIdx.x;
  int i = blockIdx.x*256 + tid;
  dinv[i] = (dsrc[i] > 0) ? rsqrtf((float)dsrc[i]) : 0.f;
  int v = in[i];
  int x = v;
  sm[tid] = x; __syncthreads();
  for (int off=1; off<256; off<<=1){
    int y = (tid >= off) ? sm[tid-off] : 0;
    __syncthreads();
    x += y; sm[tid] = x; __syncthreads();
  }
  outp[i] = x - v;
  if (tid == 255) part[blockIdx.x] = x;
}
__global__ void k_scan2(int* __restrict__ part, int nblk){
  __shared__ int sm[256];
  int tid = threadIdx.x;
  int v = (tid < nblk) ? part[tid] : 0;
  int x = v; sm[tid] = x; __syncthreads();
  for (int off=1; off<256; off<<=1){
    int y = (tid >= off) ? sm[tid-off] : 0;
    __syncthreads();
    x += y; sm[tid] = x; __syncthreads();
  }
  if (tid < nblk) part[tid] = x - v;
}
__global__ void k_scan3(const int* __restrict__ outp, const int* __restrict__ part, int* __restrict__ offs){
  int i = blockIdx.x*256 + threadIdx.x;
  offs[i] = outp[i] + part[blockIdx.x];
}
__global__ void k_csr(const int* __restrict__ ei, const float* __restrict__ dinv,
                      const int* __restrict__ offs, int* __restrict__ cursor,
                      int2* __restrict__ cedge){
  int e = blockIdx.x*256 + threadIdx.x;
  if (e < N_E){
    int s = ei[e], d = ei[N_E + e];
    int pos = atomicAdd(&cursor[d], 1);
    float w = -dinv[s]*dinv[d];
    cedge[offs[d] + pos] = make_int2(s, __float_as_int(w));
  }
}

// ---------------- x-side spmm, one t-half (6 steps) per dispatch ----------
__global__ void k_xspmm1(const unsigned short* __restrict__ Xh, unsigned short* __restrict__ AxtH,
                         unsigned short* __restrict__ Uh,
                         const int* __restrict__ offs, const int2* __restrict__ cedge){
  int n = blockIdx.x*4 + (threadIdx.x >> 6);
  int l = threadIdx.x & 63;
  if (n >= N_NODE) return;
  int beg = offs[n], end = offs[n+1];
  int ce = end - 1;
  float a[6];
#pragma unroll
  for (int t=0;t<6;++t) a[t] = 0.f;
  for (int q = beg; q < end; q += 6){
    int2 e0 = cedge[min(q,   ce)];
    int2 e1 = cedge[min(q+1, ce)];
    int2 e2 = cedge[min(q+2, ce)];
    int2 e3 = cedge[min(q+3, ce)];
    int2 e4 = cedge[min(q+4, ce)];
    int2 e5 = cedge[min(q+5, ce)];
    float w0 = __int_as_float(e0.y);
    float w1 = (q+1 < end) ? __int_as_float(e1.y) : 0.f;
    float w2 = (q+2 < end) ? __int_as_float(e2.y) : 0.f;
    float w3 = (q+3 < end) ? __int_as_float(e3.y) : 0.f;
    float w4 = (q+4 < end) ? __int_as_float(e4.y) : 0.f;
    float w5 = (q+5 < end) ? __int_as_float(e5.y) : 0.f;
    const unsigned int* r0 = (const unsigned int*)(Xh + ((size_t)e0.x*64 + l)*6);
    const unsigned int* r1 = (const unsigned int*)(Xh + ((size_t)e1.x*64 + l)*6);
    const unsigned int* r2 = (const unsigned int*)(Xh + ((size_t)e2.x*64 + l)*6);
    const unsigned int* r3 = (const unsigned int*)(Xh + ((size_t)e3.x*64 + l)*6);
    const unsigned int* r4 = (const unsigned int*)(Xh + ((size_t)e4.x*64 + l)*6);
    const unsigned int* r5 = (const unsigned int*)(Xh + ((size_t)e5.x*64 + l)*6);
    unsigned int p00=r0[0], p01=r0[1], p02=r0[2];
    unsigned int p10=r1[0], p11=r1[1], p12=r1[2];
    unsigned int p20=r2[0], p21=r2[1], p22=r2[2];
    unsigned int p30=r3[0], p31=r3[1], p32=r3[2];
    unsigned int p40=r4[0], p41=r4[1], p42=r4[2];
    unsigned int p50=r5[0], p51=r5[1], p52=r5[2];
    acc6(a, p00, p01, p02, w0);
    acc6(a, p10, p11, p12, w1);
    acc6(a, p20, p21, p22, w2);
    acc6(a, p30, p31, p32, w3);
    acc6(a, p40, p41, p42, w4);
    acc6(a, p50, p51, p52, w5);
  }
  unsigned short u[6];
#pragma unroll
  for (int t=0;t<6;++t){
    u[t] = f2bf(a[t]);
    AxtH[((size_t)t*N_PAD + n)*AXC + 64 + l] = u[t];
  }
  unsigned int* op = (unsigned int*)(Uh + ((size_t)n*64 + l)*6);
#pragma unroll
  for (int i=0;i<3;++i) op[i] = (unsigned int)u[2*i] | ((unsigned int)u[2*i+1] << 16);
}
__global__ void k_xspmm2(const unsigned short* __restrict__ Uh, unsigned short* __restrict__ AxtH,
                         const int* __restrict__ offs, const int2* __restrict__ cedge){
  int n = blockIdx.x*4 + (threadIdx.x >> 6);
  int l = threadIdx.x & 63;
  if (n >= N_NODE) return;
  int beg = offs[n], end = offs[n+1];
  int ce = end - 1;
  float a[6];
#pragma unroll
  for (int t=0;t<6;++t) a[t] = 0.f;
  for (int q = beg; q < end; q += 6){
    int2 e0 = cedge[min(q,   ce)];
    int2 e1 = cedge[min(q+1, ce)];
    int2 e2 = cedge[min(q+2, ce)];
    int2 e3 = cedge[min(q+3, ce)];
    int2 e4 = cedge[min(q+4, ce)];
    int2 e5 = cedge[min(q+5, ce)];
    float w0 = __int_as_float(e0.y);
    float w1 = (q+1 < end) ? __int_as_float(e1.y) : 0.f;
    float w2 = (q+2 < end) ? __int_as_float(e2.y) : 0.f;
    float w3 = (q+3 < end) ? __int_as_float(e3.y) : 0.f;
    float w4 = (q+4 < end) ? __int_as_float(e4.y) : 0.f;
    float w5 = (q+5 < end) ? __int_as_float(e5.y) : 0.f;
    const unsigned int* r0 = (const unsigned int*)(Uh + ((size_t)e0.x*64 + l)*6);
    const unsigned int* r1 = (const unsigned int*)(Uh + ((size_t)e1.x*64 + l)*6);
    const unsigned int* r2 = (const unsigned int*)(Uh + ((size_t)e2.x*64 + l)*6);
    const unsigned int* r3 = (const unsigned int*)(Uh + ((size_t)e3.x*64 + l)*6);
    const unsigned int* r4 = (const unsigned int*)(Uh + ((size_t)e4.x*64 + l)*6);
    const unsigned int* r5 = (const unsigned int*)(Uh + ((size_t)e5.x*64 + l)*6);
    unsigned int p00=r0[0], p01=r0[1], p02=r0[2];
    unsigned int p10=r1[0], p11=r1[1], p12=r1[2];
    unsigned int p20=r2[0], p21=r2[1], p22=r2[2];
    unsigned int p30=r3[0], p31=r3[1], p32=r3[2];
    unsigned int p40=r4[0], p41=r4[1], p42=r4[2];
    unsigned int p50=r5[0], p51=r5[1], p52=r5[2];
    acc6(a, p00, p01, p02, w0);
    acc6(a, p10, p11, p12, w1);
    acc6(a, p20, p21, p22, w2);
    acc6(a, p30, p31, p32, w3);
    acc6(a, p40, p41, p42, w4);
    acc6(a, p50, p51, p52, w5);
  }
#pragma unroll
  for (int t=0;t<6;++t)
    AxtH[((size_t)t*N_PAD + n)*AXC + 128 + l] = f2bf(a[t]);
}

// ---------------- per-step h-side spmm bodies ----------------
__device__ __forceinline__ void spmm1_body(int n, int l,
    const unsigned short* __restrict__ Hc, unsigned short* __restrict__ U,
    const int* __restrict__ offs, const int2* __restrict__ cedge)
{
  if (n >= N_NODE) return;
  int sub = l >> 4, fl = l & 15;
  int beg = offs[n], end = offs[n+1];
  int ce = end - 1;
  float a[8];
#pragma unroll
  for (int j=0;j<8;++j) a[j] = 0.f;
  for (int q = beg; q < end; q += 16){
    int i0 = q + sub, i1 = q + 4 + sub, i2 = q + 8 + sub, i3 = q + 12 + sub;
    int2 e0 = cedge[min(i0, ce)];
    int2 e1 = cedge[min(i1, ce)];
    int2 e2 = cedge[min(i2, ce)];
    int2 e3 = cedge[min(i3, ce)];
    float w0 = (i0 < end) ? __int_as_float(e0.y) : 0.f;
    float w1 = (i1 < end) ? __int_as_float(e1.y) : 0.f;
    float w2 = (i2 < end) ? __int_as_float(e2.y) : 0.f;
    float w3 = (i3 < end) ? __int_as_float(e3.y) : 0.f;
    uint4 h0 = *(const uint4*)(Hc + (size_t)e0.x*128 + fl*8);
    uint4 h1 = *(const uint4*)(Hc + (size_t)e1.x*128 + fl*8);
    uint4 h2 = *(const uint4*)(Hc + (size_t)e2.x*128 + fl*8);
    uint4 h3 = *(const uint4*)(Hc + (size_t)e3.x*128 + fl*8);
    acc8(a, h0, w0);
    acc8(a, h1, w1);
    acc8(a, h2, w2);
    acc8(a, h3, w3);
  }
#pragma unroll
  for (int j=0;j<8;++j){
    a[j] += __shfl_xor(a[j], 16);
    a[j] += __shfl_xor(a[j], 32);
  }
  if (sub == 0){
    unsigned short o[8];
#pragma unroll
    for (int j=0;j<8;++j) o[j] = f2bf(a[j]);
    *(uint4*)(U + (size_t)n*256 + fl*8) = *(const uint4*)o;
  }
}

__global__ void k_spmm2(unsigned short* __restrict__ U,
                        const int* __restrict__ offs, const int2* __restrict__ cedge){
  int n = blockIdx.x*4 + (threadIdx.x >> 6);
  int l = threadIdx.x & 63;
  if (n >= N_NODE) return;
  int sub = l >> 4, fl = l & 15;
  int beg = offs[n], end = offs[n+1];
  int ce = end - 1;
  float a[8];
#pragma unroll
  for (int j=0;j<8;++j) a[j] = 0.f;
  for (int q = beg; q < end; q += 16){
    int i0 = q + sub, i1 = q + 4 + sub, i2 = q + 8 + sub, i3 = q + 12 + sub;
    int2 e0 = cedge[min(i0, ce)];
    int2 e1 = cedge[min(i1, ce)];
    int2 e2 = cedge[min(i2, ce)];
    int2 e3 = cedge[min(i3, ce)];
    float w0 = (i0 < end) ? __int_as_float(e0.y) : 0.f;
    float w1 = (i1 < end) ? __int_as_float(e1.y) : 0.f;
    float w2 = (i2 < end) ? __int_as_float(e2.y) : 0.f;
    float w3 = (i3 < end) ? __int_as_float(e3.y) : 0.f;
    uint4 h0 = *(const uint4*)(U + (size_t)e0.x*256 + fl*8);
    uint4 h1 = *(const uint4*)(U + (size_t)e1.x*256 + fl*8);
    uint4 h2 = *(const uint4*)(U + (size_t)e2.x*256 + fl*8);
    uint4 h3 = *(const uint4*)(U + (size_t)e3.x*256 + fl*8);
    acc8(a, h0, w0);
    acc8(a, h1, w1);
    acc8(a, h2, w2);
    acc8(a, h3, w3);
  }
#pragma unroll
  for (int j=0;j<8;++j){
    a[j] += __shfl_xor(a[j], 16);
    a[j] += __shfl_xor(a[j], 32);
  }
  if (sub == 0){
    unsigned short o[8];
#pragma unroll
    for (int j=0;j<8;++j) o[j] = f2bf(a[j]);
    *(uint4*)(U + (size_t)n*256 + 128 + fl*8) = *(const uint4*)o;
  }
}

// ---------------- LN + MLP body ----------------
__device__ __forceinline__ void lnmlp_body(int n0,
    const unsigned short* __restrict__ Hn,
    const unsigned short* __restrict__ W1t, const float* __restrict__ b1p,
    const float* __restrict__ W2p, const float* __restrict__ b2,
    const float* __restrict__ gam, const float* __restrict__ bet,
    float* __restrict__ out, int t)
{
  __shared__ __align__(16) unsigned short xn[64*128];
  __shared__ __align__(16) unsigned short w1s[HID_P*128];
  __shared__ float w2s[HID_P*2];
  __shared__ float b1s[HID_P];
  __shared__ float b2s[2];
  int tid = threadIdx.x;
  for (int i = tid; i < HID_P*128/8; i += 256) ((int4*)w1s)[i] = ((const int4*)W1t)[i];
  if (tid < HID_P*2) w2s[tid] = W2p[tid];
  if (tid < HID_P)   b1s[tid] = b1p[tid];
  if (tid < 2)       b2s[tid] = b2[tid];
  int row = tid >> 2, part = tid & 3;
  int n = n0 + row;
  float vals[32];
  float s = 0.f, ss = 0.f;
  if (n < N_NODE){
    const unsigned short* hp = Hn + (size_t)n*128 + part*32;
#pragma unroll
    for (int k=0;k<32;++k){
      float x = ftanh(bf2f(hp[k]));
      vals[k] = x; s += x; ss += x*x;
    }
  } else {
#pragma unroll
    for (int k=0;k<32;++k) vals[k] = 0.f;
  }
  s  += __shfl_xor(s,1);  s  += __shfl_xor(s,2);
  ss += __shfl_xor(ss,1); ss += __shfl_xor(ss,2);
  float mu = s * (1.f/128.f);
  float var = ss * (1.f/128.f) - mu*mu;
  float inv = rsqrtf(fmaxf(var, 0.f) + 1e-5f);
#pragma unroll
  for (int k=0;k<32;++k){
    int d = part*32 + k;
    xn[row*128 + d] = f2bf((vals[k]-mu)*inv*gam[d] + bet[d]);
  }
  __syncthreads();
  int w = tid >> 6, l = tid & 63;
  const f32x4 vzero = {0.f,0.f,0.f,0.f};
  f32x4 acc[5];
#pragma unroll
  for (int tj=0;tj<5;++tj) acc[tj] = vzero;
#pragma unroll
  for (int kk=0;kk<4;++kk){
    bf16x8 a = *(const bf16x8*)(xn + (w*16 + (l&15))*128 + kk*32 + (l>>4)*8);
#pragma unroll
    for (int tj=0;tj<5;++tj){
      bf16x8 b = *(const bf16x8*)(w1s + (tj*16 + (l&15))*128 + kk*32 + (l>>4)*8);
      acc[tj] = __builtin_amdgcn_mfma_f32_16x16x32_bf16(a, b, acc[tj], 0,0,0);
    }
  }
#pragma unroll
  for (int r=0;r<4;++r){
    int rn = n0 + w*16 + (l>>4)*4 + r;
    float p0 = 0.f, p1 = 0.f;
#pragma unroll
    for (int tj=0;tj<5;++tj){
      int col = tj*16 + (l&15);
      float hv = fmaxf(acc[tj][r] + b1s[col], 0.f);
      p0 += hv * w2s[col*2];
      p1 += hv * w2s[col*2+1];
    }
    p0 += __shfl_xor(p0,1); p0 += __shfl_xor(p0,2); p0 += __shfl_xor(p0,4); p0 += __shfl_xor(p0,8);
    p1 += __shfl_xor(p1,1); p1 += __shfl_xor(p1,2); p1 += __shfl_xor(p1,4); p1 += __shfl_xor(p1,8);
    if ((l & 15) == 0 && rn < N_NODE){
      float* op = out + (size_t)rn*24 + t;
      op[0]  = sigf(p0 + b2s[0]);
      op[12] = sigf(p1 + b2s[1]);
    }
  }
}

// ---------------- horizontal fusion: spmm1(t) || lnmlp(t-1) ----------------
__global__ void k_sp1ln(const unsigned short* __restrict__ Hc, unsigned short* __restrict__ U,
                        const int* __restrict__ offs, const int2* __restrict__ cedge,
                        const unsigned short* __restrict__ W1t, const float* __restrict__ b1p,
                        const float* __restrict__ W2p, const float* __restrict__ b2,
                        const float* __restrict__ gam, const float* __restrict__ bet,
                        float* __restrict__ out, int tprev)
{
  int bb = blockIdx.x;
  if (bb < NB_SPMM){
    spmm1_body(bb*4 + (threadIdx.x >> 6), threadIdx.x & 63, Hc, U, offs, cedge);
  } else {
    lnmlp_body((bb - NB_SPMM)*64, Hc, W1t, b1p, W2p, b2, gam, bet, out, tprev);
  }
}

__global__ __launch_bounds__(256,2) void k_lnmlp(const unsigned short* __restrict__ Hn,
                        const unsigned short* __restrict__ W1t, const float* __restrict__ b1p,
                        const float* __restrict__ W2p, const float* __restrict__ b2,
                        const float* __restrict__ gam, const float* __restrict__ bet,
                        float* __restrict__ out, int t)
{
  lnmlp_body(blockIdx.x*64, Hn, W1t, b1p, W2p, b2, gam, bet, out, t);
}

// ---------------- fused GEMM + LSTM gates (single-buf, 3 blocks/CU) ----------
__global__ __launch_bounds__(256,3) void k_gemm(
    const unsigned short* __restrict__ Hc, const unsigned short* __restrict__ U,
    const unsigned short* __restrict__ Axt,
    const unsigned short* __restrict__ Bct, const float* __restrict__ btot,
    const float* __restrict__ wc, float* __restrict__ c, unsigned short* __restrict__ Hn,
    int it0)
{
  __shared__ __align__(16) unsigned short As[128*64];
  __shared__ __align__(16) unsigned short Bs[128*64];
  int tid = threadIdx.x;
  int w = tid >> 6, l = tid & 63;
  const int NWG = 1564, q8 = NWG >> 3, r8 = NWG & 7;
  int L = blockIdx.y*4 + blockIdx.x;
  int xcd = L & 7, li = L >> 3;
  int W = (xcd < r8 ? xcd*(q8+1) : r8*(q8+1) + (xcd-r8)*q8) + li;
  int bx = W & 3, by = W >> 2;
  int n0 = bx * 128;
  int m0 = by * 128;
  const f32x4 vzero = {0.f,0.f,0.f,0.f};
  f32x4 acc[4][4];
#pragma unroll
  for (int i=0;i<4;++i)
#pragma unroll
    for (int j=0;j<4;++j) acc[i][j] = vzero;
  int wr = w >> 1, wn = w & 1;
  for (int it=it0; it<9; ++it){
    const unsigned short* Ab; int astr, acol;
    if (it < 2)      { Ab = Hc;  astr = 128; acol = it*64; }
    else if (it < 6) { Ab = U;   astr = 256; acol = (it-2)*64; }
    else             { Ab = Axt; astr = AXC; acol = (it-6)*64; }
    if (it != it0) __syncthreads();
#pragma unroll
    for (int i=0;i<4;++i){
      int rr = w*32 + i*8;
      int row = rr + (l>>3);
      gload16(Ab  + (size_t)(m0+row)*astr + acol + (l&7)*8, (void*)(As + rr*64));
      gload16(Bct + (size_t)(n0+row)*K_TOT + it*64 + (l&7)*8, (void*)(Bs + rr*64));
    }
    __syncthreads();
#pragma unroll
    for (int kk=0; kk<2; ++kk){
      bf16x8 af[4], bfv[4];
#pragma unroll
      for (int i=0;i<4;++i) af[i]  = *(const bf16x8*)(As + (wr*64 + i*16 + (l&15))*64 + kk*32 + (l>>4)*8);
#pragma unroll
      for (int j=0;j<4;++j) bfv[j] = *(const bf16x8*)(Bs + (wn*64 + j*16 + (l&15))*64 + kk*32 + (l>>4)*8);
#pragma unroll
      for (int i=0;i<4;++i)
#pragma unroll
        for (int j=0;j<4;++j)
          acc[i][j] = __builtin_amdgcn_mfma_f32_16x16x32_bf16(af[i], bfv[j], acc[i][j], 0,0,0);
    }
  }
  int dd = (((bx<<1) + wn) << 4) | (l & 15);
  float b_i = btot[dd], b_f = btot[128+dd], b_t = btot[256+dd], b_o = btot[384+dd];
  float wci = wc[dd], wcf = wc[128+dd], wco = wc[256+dd];
#pragma unroll
  for (int i=0;i<4;++i){
    int row0 = m0 + wr*64 + i*16 + (l>>4)*4;
#pragma unroll
    for (int r=0;r<4;++r){
      int row = row0 + r;
      float co = c[(size_t)row*128 + dd];
      float gi = sigf(acc[i][0][r] + b_i + wci*co);
      float gf = sigf(acc[i][1][r] + b_f + wcf*co);
      float tt = ftanh(acc[i][2][r] + b_t);
      float cn = gf*co + gi*tt;
      float go = sigf(acc[i][3][r] + b_o + wco*cn);
      float h = go * ftanh(cn);
      c[(size_t)row*128 + dd] = cn;
      Hn[(size_t)row*128 + dd] = f2bf(h);
    }
  }
}

extern "C" void kernel_launch(void* const* d_in, const int* in_sizes, int n_in,
                              void* d_out, int out_size, void* d_ws, size_t ws_size,
                              hipStream_t stream)
{
  const float* H   = (const float*)d_in[0];
  const int*   ei  = (const int*)d_in[1];
  const float* Wx  = (const float*)d_in[2];
  const float* bx  = (const float*)d_in[3];
  const float* Wh  = (const float*)d_in[4];
  const float* bh  = (const float*)d_in[5];
  const float* bg  = (const float*)d_in[6];
  const float* wc  = (const float*)d_in[7];
  const float* gam = (const float*)d_in[8];
  const float* bet = (const float*)d_in[9];
  const float* W1  = (const float*)d_in[10];
  const float* b1  = (const float*)d_in[11];
  const float* W2  = (const float*)d_in[12];
  const float* b2  = (const float*)d_in[13];
  float* out = (float*)d_out;
  (void)in_sizes; (void)n_in; (void)out_size; (void)ws_size;

  char* p = (char*)d_ws;
  auto alloc = [&](size_t bytes)->char*{ char* r = p; p += (bytes + 255) & ~(size_t)255; return r; };
  // ---- zeroed region ----
  char* zbase = p;
  float* c_st  = (float*)alloc((size_t)N_PAD*128*4);
  int* dsrc   = (int*)alloc((size_t)N_P2*4);
  int* ddst   = (int*)alloc((size_t)N_P2*4);
  int* cursor = (int*)alloc((size_t)N_P2*4);
  size_t zbytes = (size_t)(p - zbase);
  // ---- rest ----
  unsigned short* Hbuf0 = (unsigned short*)alloc((size_t)N_PAD*128*2);
  unsigned short* Hbuf1 = (unsigned short*)alloc((size_t)N_PAD*128*2);
  unsigned short* Ubuf  = (unsigned short*)alloc((size_t)N_PAD*256*2);
  unsigned short* Xtr   = (unsigned short*)alloc((size_t)N_PAD*768*2);   // 2 halves x [n*64+d][6]
  unsigned short* U1tr  = (unsigned short*)alloc((size_t)N_PAD*768*2);
  unsigned short* Axt   = (unsigned short*)alloc((size_t)S_DIM*N_PAD*AXC*2);
  unsigned short* Bct   = (unsigned short*)alloc((size_t)N_COL*K_TOT*2);
  float*          btot  = (float*)alloc(N_COL*4);
  unsigned short* W1t   = (unsigned short*)alloc(HID_P*128*2);
  float*          b1p   = (float*)alloc(HID_P*4);
  float*          W2p   = (float*)alloc(HID_P*2*4);
  float*          dinv  = (float*)alloc((size_t)N_P2*4);
  int*            offs  = (int*)alloc((size_t)(N_P2+256)*4);
  int*            outp  = (int*)alloc((size_t)N_P2*4);
  int*            partb = (int*)alloc(256*4);
  int2*           cedge = (int2*)alloc((size_t)N_E*8);

  hipMemsetAsync(zbase, 0, zbytes, stream);
  k_setup<<<NB_PREP + NB_XPREP + NB_DEG, 256, 0, stream>>>(H, ei, Wx, Wh, bx, bh, bg,
      W1, b1, W2, Bct, btot, W1t, b1p, W2p, Xtr, Axt, dsrc, ddst);
  k_scan1d<<<N_P2/256, 256, 0, stream>>>(ddst, outp, partb, dsrc, dinv);
  k_scan2<<<1, 256, 0, stream>>>(partb, N_P2/256);
  k_scan3<<<N_P2/256, 256, 0, stream>>>(outp, partb, offs);
  k_csr<<<NB_DEG, 256, 0, stream>>>(ei, dinv, offs, cursor, cedge);
  for (int h = 0; h < 2; ++h){
    k_xspmm1<<<NB_SPMM, 256, 0, stream>>>(Xtr + (size_t)h*N_PAD*384,
        Axt + (size_t)h*6*N_PAD*AXC, U1tr + (size_t)h*N_PAD*384, offs, cedge);
  }
  for (int h = 0; h < 2; ++h){
    k_xspmm2<<<NB_SPMM, 256, 0, stream>>>(U1tr + (size_t)h*N_PAD*384,
        Axt + (size_t)h*6*N_PAD*AXC, offs, cedge);
  }

  // t = 0: h == 0 -> only x-part of K (it0 = 6); Hc/U never read.
  k_gemm<<<dim3(4, N_PAD/128), 256, 0, stream>>>(Hbuf0, Ubuf, Axt,
      Bct, btot, wc, c_st, Hbuf1, 6);
  for (int t = 1; t < S_DIM; ++t){
    unsigned short* Hc = (t & 1) ? Hbuf1 : Hbuf0;
    unsigned short* Hn = (t & 1) ? Hbuf0 : Hbuf1;
    k_sp1ln<<<NB_SPMM + NB_LN, 256, 0, stream>>>(Hc, Ubuf, offs, cedge,
        W1t, b1p, W2p, b2, gam, bet, out, t-1);
    k_spmm2<<<NB_SPMM, 256, 0, stream>>>(Ubuf, offs, cedge);
    k_gemm<<<dim3(4, N_PAD/128), 256, 0, stream>>>(Hc, Ubuf,
        Axt + (size_t)t*N_PAD*AXC, Bct, btot, wc, c_st, Hn, 0);
  }
  k_lnmlp<<<NB_LN, 256, 0, stream>>>(Hbuf0, W1t, b1p, W2p, b2, gam, bet, out, 11);
}